// Round 7
// baseline (381.152 us; speedup 1.0000x reference)
//
#include <hip/hip_runtime.h>
#include <hip/hip_bf16.h>

#define IN_F 256
#define NN   2048
#define BB   8

typedef unsigned short u16;
typedef __attribute__((ext_vector_type(8))) short short8x;   // 8 bf16 = 4 VGPRs
typedef __attribute__((ext_vector_type(4))) float float4x;   // MFMA acc

// fp32 -> bf16 bits, round-to-nearest-even
__device__ __forceinline__ u16 f2b(float f) {
    union { float f; unsigned int u; } x; x.f = f;
    unsigned int r = x.u + 0x7FFFu + ((x.u >> 16) & 1u);
    return (u16)(r >> 16);
}

// ---------------------------------------------------------------------------
// prep: fused transposes + calc_v.  v8: G13-vectorized (float4 global loads,
// LDS-transposed, ushort4 stores) — the old version did scalar 4B loads and
// scalar 2B stores (~2-2.5x slow per guide m12/m146).
// ---------------------------------------------------------------------------
__device__ __forceinline__ void transp_body4(const float* __restrict__ src,
                                             u16* __restrict__ dst,
                                             int R, int C, int tid,
                                             float (*tile)[33])
{
    const int per = (R / 32) * (C / 32);
    const int b  = tid / per;
    const int tt = tid % per;
    const int jt = tt / (C / 32);
    const int ct = tt % (C / 32);
    src += (long)b * R * C;
    dst += (long)b * R * C;

    const int t = threadIdx.x;
    // load: row lr (32), col group lc (8 x float4) — 128B per 8 lanes, coalesced
    const int lr = t >> 3, lc = (t & 7) * 4;
    float4 v = *(const float4*)(src + (long)(jt * 32 + lr) * C + ct * 32 + lc);
    tile[lr][lc + 0] = v.x;   // stride-33 rows: (r+c)%32 banks -> <=2-way (free)
    tile[lr][lc + 1] = v.y;
    tile[lr][lc + 2] = v.z;
    tile[lr][lc + 3] = v.w;
    __syncthreads();
    // store: col c (32), row group r4 — ushort4 (8B), 64B contiguous per 8 lanes
    const int c = t >> 3, r4 = (t & 7) * 4;
    ushort4 o;
    o.x = f2b(tile[r4 + 0][c]);
    o.y = f2b(tile[r4 + 1][c]);
    o.z = f2b(tile[r4 + 2][c]);
    o.w = f2b(tile[r4 + 3][c]);
    *(ushort4*)(dst + (long)(ct * 32 + c) * R + jt * 32 + r4) = o;
}

__global__ __launch_bounds__(256) void prep(const float* __restrict__ h,
                                            const float* __restrict__ g,
                                            const float* __restrict__ W1,
                                            const float* __restrict__ W2,
                                            const float* __restrict__ a,
                                            u16* __restrict__ HbfT,
                                            u16* __restrict__ GbfT,
                                            u16* __restrict__ W1T,
                                            u16* __restrict__ W2T,
                                            float* __restrict__ v1,
                                            float* __restrict__ v2)
{
    __shared__ float tile[32][33];
    __shared__ float s1[IN_F], s2[IN_F];
    const int bid = blockIdx.x;

    if (bid < 4096) {
        transp_body4(h, HbfT, NN, IN_F, bid, tile);
    } else if (bid < 8192) {
        transp_body4(g, GbfT, NN, IN_F, bid - 4096, tile);
    } else if (bid < 8256) {
        transp_body4(W1, W1T, IN_F, IN_F, bid - 8192, tile);
    } else if (bid < 8320) {
        transp_body4(W2, W2T, IN_F, IN_F, bid - 8256, tile);
    } else {
        const int t = threadIdx.x;
        s1[t] = a[t];
        s2[t] = a[IN_F + t];
        __syncthreads();
        float acc1 = 0.f, acc2 = 0.f;
        for (int c = 0; c < IN_F; ++c) {
            float w = W1[t * IN_F + c];
            acc1 += w * s1[c];
            acc2 += w * s2[c];
        }
        v1[t] = acc1;
        v2[t] = acc2;
    }
}

// ---------------------------------------------------------------------------
// rowdots: Wh1[row] = h[row,:]·v1, Wh2[row] = h[row,:]·v2. One wave per row.
// ---------------------------------------------------------------------------
__global__ __launch_bounds__(256) void rowdots(const float* __restrict__ h,
                                               const float* __restrict__ v1,
                                               const float* __restrict__ v2,
                                               float* __restrict__ Wh1,
                                               float* __restrict__ Wh2)
{
    const int wave = threadIdx.x >> 6;
    const int lane = threadIdx.x & 63;
    const long row = (long)blockIdx.x * 4 + wave;
    const int c0 = lane * 4;

    float4 v  = *(const float4*)(h + row * IN_F + c0);
    float4 a1 = *(const float4*)(v1 + c0);
    float4 a2 = *(const float4*)(v2 + c0);

    float s1 = v.x * a1.x + v.y * a1.y + v.z * a1.z + v.w * a1.w;
    float s2 = v.x * a2.x + v.y * a2.y + v.z * a2.z + v.w * a2.w;
#pragma unroll
    for (int off = 32; off; off >>= 1) {
        s1 += __shfl_xor(s1, off, 64);
        s2 += __shfl_xor(s2, off, 64);
    }
    if (lane == 0) { Wh1[row] = s1; Wh2[row] = s2; }
}

// ---------------------------------------------------------------------------
// attn_mfma v8: 16 waves/CU (the untouched knob).
// Accounting: per SIMD per chunk only ~8% of cycles are issue (640 MFMA +
// ~600 VALU of 15.1k) — pure latency stall with just 2 waves/SIMD to hide it.
// All prior theories rearranged those 2 waves; none ADDED waves.  v8:
//  * BM=32, matrix-split -> grid 1024 x 256 thr; __launch_bounds__(256,4)
//    -> 4 blocks/CU x 4 waves = 16 waves/CU (VGPR cap 128, m69).
//  * wave = 32 rows x 64 cols: acc[2][4]=32 VGPR, 8 MFMA/kstep, B ping-pong
//    (v3/v7-proven schedule otherwise unchanged, lgkm-only barrier).
//  * adj via 1-reg bitmask: thread loads its OWN 16 adj ints for chunk K+1
//    (transient int4 x4) during chunk K's MFMA phase, packs to 16 bits ->
//    replaces v7's 64-VGPR adj double-buffer.  vmcnt wait (pack) lands
//    after the MFMA issues; in-order retirement leaves B loads in flight.
//  * LDS 25.3KB/block (2x8KB Afrag + 8KB wh2 + red) -> 4 blocks = 101KB OK.
// Cost: B-panel L2 traffic doubles (~1GB, ~29us at L2 aggregate) — acceptable
// if the latency theory is right.  Tripwires: VGPR<=128, WRITE~16.4MB.
// ---------------------------------------------------------------------------
#define KS8(KSV, BC, BN_, jnxt)                                               \
    {                                                                         \
        short8x Ar0 = *(const short8x*)&ab[(((KSV) * 2 + 0) * 64 + lane) * 8];\
        short8x Ar1 = *(const short8x*)&ab[(((KSV) * 2 + 1) * 64 + lane) * 8];\
        _Pragma("unroll") for (int ct = 0; ct < 4; ++ct)                      \
            BN_[ct] = *(const short8x*)(Bp + ct * 16 * NN + (jnxt));          \
        _Pragma("unroll") for (int ct = 0; ct < 4; ++ct) {                    \
            acc[0][ct] = __builtin_amdgcn_mfma_f32_16x16x32_bf16(Ar0, BC[ct], acc[0][ct], 0, 0, 0); \
            acc[1][ct] = __builtin_amdgcn_mfma_f32_16x16x32_bf16(Ar1, BC[ct], acc[1][ct], 0, 0, 0); \
        }                                                                     \
    }

#define PK4(I4, BASE)                                                         \
    pb |= ((unsigned)(I4.x > 0) << (BASE))     | ((unsigned)(I4.y > 0) << ((BASE)+1)) | \
          ((unsigned)(I4.z > 0) << ((BASE)+2)) | ((unsigned)(I4.w > 0) << ((BASE)+3));

#define CHUNK8(KCH)                                                           \
    {                                                                         \
        const int j0 = (KCH) * 128;                                           \
        union { short8x v; u16 e[8]; } pk0, pk1;                              \
        _Pragma("unroll") for (int u = 0; u < 4; ++u) {                       \
            const float4 wv = *(const float4*)&wh2L[j0 + sg * 16 + u * 4];    \
            const float wf[4] = {wv.x, wv.y, wv.z, wv.w};                     \
            _Pragma("unroll") for (int c = 0; c < 4; ++c) {                   \
                float x = wh1rr + wf[c];                                      \
                float ev = fmaxf(x, 0.2f * x);                                \
                float p = __expf(ev - mv);                                    \
                p = ((mk >> (u * 4 + c)) & 1u) ? p : 0.0f;                    \
                lloc += p;                                                    \
                u16 fv = f2b(p);                                              \
                if (u < 2) pk0.e[u * 4 + c] = fv;                             \
                else       pk1.e[(u - 2) * 4 + c] = fv;                       \
            }                                                                 \
        }                                                                     \
        if ((KCH) < 15) {                                                     \
            const long o = adjR + ((KCH) + 1) * 128 + sg * 16;                \
            i0 = *(const int4*)(adj + o);                                     \
            i1 = *(const int4*)(adj + o + 4);                                 \
            i2 = *(const int4*)(adj + o + 8);                                 \
            i3 = *(const int4*)(adj + o + 12);                                \
        }                                                                     \
        u16* ab = &Afrag[(KCH) & 1][0];                                       \
        *(short8x*)&ab[wbase0]       = pk0.v;                                 \
        *(short8x*)&ab[wbase0 + 128] = pk1.v;                                 \
        asm volatile("s_waitcnt lgkmcnt(0)\n\ts_barrier" ::: "memory");       \
        KS8(0, B0, B1, j0 + 1 * 32 + bq8)                                     \
        KS8(1, B1, B0, j0 + 2 * 32 + bq8)                                     \
        KS8(2, B0, B1, j0 + 3 * 32 + bq8)                                     \
        KS8(3, B1, B0, (((KCH) < 15) ? (j0 + 128) : j0) + bq8)                \
        if ((KCH) < 15) {                                                     \
            unsigned pb = 0;                                                  \
            PK4(i0, 0) PK4(i1, 4) PK4(i2, 8) PK4(i3, 12)                      \
            mk = pb;                                                          \
        }                                                                     \
    }

__global__ __launch_bounds__(256, 4) void attn_mfma(
    const int* __restrict__ adj,
    const u16* __restrict__ HbfT, const u16* __restrict__ GbfT,
    const float* __restrict__ Wh1, const float* __restrict__ Wh2,
    u16* __restrict__ PH, u16* __restrict__ PG)
{
    const int t = threadIdx.x;
    const int wave = t >> 6, lane = t & 63;
    // bid -> (batch=XCD, matrix, row-block).  H/G pair = bids 8 apart:
    // adjacent dispatch on the same XCD -> shared adj slice L2-hits.
    const int b   = blockIdx.x & 7;
    const int idx = blockIdx.x >> 3;           // [0,128) within batch
    const int mat = idx & 1;                   // 0 = H, 1 = G
    const int rbl = idx >> 1;                  // [0,64) row-block in batch
    const long gi0 = ((long)b * 64 + rbl) * 32;   // BM=32

    __shared__ __align__(16) u16 Afrag[2][4096];   // 2 x 8 KB (4 ksteps x 2 rt)
    __shared__ float wh2L[2048];                   // 8 KB: batch Wh2 slice
    __shared__ float sred[256];
    __shared__ float ssc[33];                      // [0..31]=1/l, [32]=wh2max

    // p-compute role: row rr (32 rows), sg (8) -> 16 consecutive j per chunk
    const int rr = t >> 3, sg = t & 7;
    const long adjR = (gi0 + rr) * (long)NN;
    const float* wh2b = Wh2 + (long)b * NN;
    const float wh1rr = Wh1[gi0 + rr];

    // ---- stage Wh2 slice to LDS + per-batch max ----
    {
        float4 w0 = *(const float4*)(wh2b + t * 8);
        float4 w1 = *(const float4*)(wh2b + t * 8 + 4);
        *(float4*)&wh2L[t * 8]     = w0;
        *(float4*)&wh2L[t * 8 + 4] = w1;
        float m = fmaxf(fmaxf(fmaxf(w0.x, w0.y), fmaxf(w0.z, w0.w)),
                        fmaxf(fmaxf(w1.x, w1.y), fmaxf(w1.z, w1.w)));
        sred[t] = m;
    }
    __syncthreads();
    if (t < 64) {
        float v = fmaxf(fmaxf(sred[t * 4], sred[t * 4 + 1]),
                        fmaxf(sred[t * 4 + 2], sred[t * 4 + 3]));
#pragma unroll
        for (int off = 32; off; off >>= 1) v = fmaxf(v, __shfl_xor(v, off, 64));
        if (t == 0) ssc[32] = v;
    }
    __syncthreads();
    const float mm = wh1rr + ssc[32];
    const float mv = (mm >= 0.f) ? mm : 0.2f * mm;   // lrelu upper bound >= all logits

    // A-fragment write slot: thread (rr, sg) covers j_local = sg*16 + e:
    // frag = (sg>>1)*2 + (rr>>4... rr<32 so rt=rr>>4 in {0,1}), lane =
    // (rr&15) + 16*(2*(sg&1) + (e>>3)), elem = e&7.  Two b128 at +0/+128.
    const int wbase0 = ((sg >> 1) * 2 + (rr >> 4)) * 512
                     + ((rr & 15) + 32 * (sg & 1)) * 8;

    float4x acc[2][4];
#pragma unroll
    for (int rt = 0; rt < 2; ++rt)
#pragma unroll
        for (int ct = 0; ct < 4; ++ct) acc[rt][ct] = (float4x)0.0f;

    const int bn = lane & 15, bq = lane >> 4, bq8 = bq * 8;
    // wave -> 64-col slice of this block's matrix
    const u16* Bp = (mat ? GbfT : HbfT) + (long)b * IN_F * NN
                  + (long)(wave * 64 + bn) * NN;

    float lloc = 0.f;
    unsigned mk = 0;
    int4 i0, i1, i2, i3;
    short8x B0[4], B1[4];

    // ---- prologue: adj chunk 0 -> mk; B group (kch=0, ks=0) ----
    i0 = *(const int4*)(adj + adjR + sg * 16);
    i1 = *(const int4*)(adj + adjR + sg * 16 + 4);
    i2 = *(const int4*)(adj + adjR + sg * 16 + 8);
    i3 = *(const int4*)(adj + adjR + sg * 16 + 12);
    {
        unsigned pb = 0;
        PK4(i0, 0) PK4(i1, 4) PK4(i2, 8) PK4(i3, 12)
        mk = pb;
    }
#pragma unroll
    for (int ct = 0; ct < 4; ++ct)
        B0[ct] = *(const short8x*)(Bp + ct * 16 * NN + bq8);

    for (int kp = 0; kp < 8; ++kp) {
        CHUNK8(kp * 2)
        CHUNK8(kp * 2 + 1)
    }

    // ---- reduce l per row (8 partials/row), invert ----
    sred[t] = lloc;
    __syncthreads();
    if (t < 32) {
        float v = sred[t * 8];
#pragma unroll
        for (int k = 1; k < 8; ++k) v += sred[t * 8 + k];
        ssc[t] = 1.0f / v;       // v > 0 always (~half the j's unmasked)
    }
    __syncthreads();

    // ---- scale by 1/l and store (C-layout: col=lane&15, row=(lane>>4)*4+reg)
    u16* dst = mat ? PG : PH;
    const int colb = wave * 64;
#pragma unroll
    for (int rt = 0; rt < 2; ++rt)
#pragma unroll
        for (int ct = 0; ct < 4; ++ct) {
            const int c = colb + ct * 16 + bn;
#pragma unroll
            for (int reg = 0; reg < 4; ++reg) {
                const int rl = rt * 16 + bq * 4 + reg;
                const float il = ssc[rl];
                const long row = gi0 + rl;
                dst[row * IN_F + c] = f2b(acc[rt][ct][reg] * il);
            }
        }
}

// ---------------------------------------------------------------------------
// epi2: both epilogue GEMMs in one launch.
// blocks [0,512): out0 = ELU(PH @ W1); blocks [512,1024): out1 = ELU(PG @ W2)
// ---------------------------------------------------------------------------
__global__ __launch_bounds__(256) void epi2(const u16* __restrict__ PH,
                                            const u16* __restrict__ PG,
                                            const u16* __restrict__ W1T,
                                            const u16* __restrict__ W2T,
                                            float* __restrict__ out)
{
    int bid = blockIdx.x;
    const u16* X;
    const u16* WT;
    float* o;
    if (bid < 512) { X = PH; WT = W1T; o = out; }
    else           { X = PG; WT = W2T; o = out + (long)BB * NN * IN_F; bid -= 512; }

    const int t = threadIdx.x;
    const int wave = t >> 6, lane = t & 63;
    const long i0 = (long)bid * 32;

    __shared__ __align__(16) u16 Afrag[8 * 2 * 64 * 8];   // 16 KB

    const int m = t >> 3, ks0 = t & 7, rt0 = m >> 4, lm = m & 15;
    const u16* xp = X + (i0 + m) * IN_F + ks0 * 32;
#pragma unroll
    for (int q = 0; q < 4; ++q) {
        short8x v = *(const short8x*)(xp + q * 8);
        *(short8x*)&Afrag[((ks0 * 2 + rt0) * 64 + lm + q * 16) * 8] = v;
    }
    __syncthreads();

    float4x acc[2][4];
#pragma unroll
    for (int rt = 0; rt < 2; ++rt)
#pragma unroll
        for (int ct = 0; ct < 4; ++ct) acc[rt][ct] = (float4x)0.0f;

    const int bn = lane & 15, bq = lane >> 4;
#pragma unroll
    for (int ks = 0; ks < 8; ++ks) {
        short8x A0 = *(const short8x*)&Afrag[((ks * 2 + 0) * 64 + lane) * 8];
        short8x A1 = *(const short8x*)&Afrag[((ks * 2 + 1) * 64 + lane) * 8];
#pragma unroll
        for (int ct = 0; ct < 4; ++ct) {
            const int n = wave * 64 + ct * 16 + bn;
            short8x Bw = *(const short8x*)(WT + n * IN_F + ks * 32 + bq * 8);
            acc[0][ct] = __builtin_amdgcn_mfma_f32_16x16x32_bf16(A0, Bw, acc[0][ct], 0, 0, 0);
            acc[1][ct] = __builtin_amdgcn_mfma_f32_16x16x32_bf16(A1, Bw, acc[1][ct], 0, 0, 0);
        }
    }

#pragma unroll
    for (int rt = 0; rt < 2; ++rt)
#pragma unroll
        for (int ct = 0; ct < 4; ++ct) {
            const int n = wave * 64 + ct * 16 + bn;
#pragma unroll
            for (int reg = 0; reg < 4; ++reg) {
                const long row = i0 + rt * 16 + bq * 4 + reg;
                float v = acc[rt][ct][reg];
                v = (v > 0.f) ? v : (__expf(v) - 1.f);   // ELU
                o[row * IN_F + n] = v;
            }
        }
}

// ---------------------------------------------------------------------------
extern "C" void kernel_launch(void* const* d_in, const int* in_sizes, int n_in,
                              void* d_out, int out_size, void* d_ws, size_t ws_size,
                              hipStream_t stream)
{
    int ih = -1, ig = -1, iadj = -1, iw1 = -1, iw2 = -1, ia = -1;
    for (int i = 0; i < n_in; ++i) {
        int s = in_sizes[i];
        if      (s == BB * NN * NN)   { if (iadj < 0) iadj = i; }
        else if (s == BB * NN * IN_F) { if (ih < 0) ih = i; else if (ig < 0) ig = i; }
        else if (s == IN_F * IN_F)    { if (iw1 < 0) iw1 = i; else if (iw2 < 0) iw2 = i; }
        else if (s == 2 * IN_F)       { if (ia < 0) ia = i; }
    }
    if (ih < 0 || ig < 0 || iadj < 0 || iw1 < 0 || iw2 < 0 || ia < 0) {
        ih = 0; iadj = 1; ig = 2; iw1 = 3; iw2 = 4; ia = 5;
    }
    const float* h     = (const float*)d_in[ih];
    const int*   adj   = (const int*)  d_in[iadj];
    const float* lrgt1 = (const float*)d_in[ig];
    const float* W1    = (const float*)d_in[iw1];
    const float* W2    = (const float*)d_in[iw2];
    const float* a     = (const float*)d_in[ia];
    float* out = (float*)d_out;

    // ws layout — 33,949,696 B total (<= proven-available 34,212,096 B)
    float* ws   = (float*)d_ws;
    float* v1   = ws;                       // 256
    float* v2   = v1 + IN_F;                // 256
    float* Wh1  = v2 + IN_F;                // 16384
    float* Wh2  = Wh1 + BB * NN;            // 16384
    u16* W1T  = (u16*)(Wh2 + BB * NN);      // 65536 bf16
    u16* W2T  = W1T + IN_F * IN_F;          // 65536
    u16* HbfT = W2T + IN_F * IN_F;          // 8*256*2048
    u16* GbfT = HbfT + (long)BB * IN_F * NN;
    u16* PH   = GbfT + (long)BB * IN_F * NN;
    u16* PG   = PH + (long)BB * NN * IN_F;

    const int nrows = BB * NN;

    prep     <<<8321,        256, 0, stream>>>(h, lrgt1, W1, W2, a,
                                               HbfT, GbfT, W1T, W2T, v1, v2);
    rowdots  <<<nrows / 4,   256, 0, stream>>>(h, v1, v2, Wh1, Wh2);
    attn_mfma<<<2 * nrows / 32, 256, 0, stream>>>(adj, HbfT, GbfT, Wh1, Wh2, PH, PG);
    epi2     <<<2 * nrows / 32, 256, 0, stream>>>(PH, PG, W1T, W2T, out);
}

// Round 8
// 344.334 us; speedup vs baseline: 1.1069x; 1.1069x over previous
//
#include <hip/hip_runtime.h>
#include <hip/hip_bf16.h>

#define IN_F 256
#define NN   2048
#define BB   8

typedef unsigned short u16;
typedef unsigned long long u64;
typedef __attribute__((ext_vector_type(8))) short short8x;   // 8 bf16 = 4 VGPRs
typedef __attribute__((ext_vector_type(4))) float float4x;   // MFMA acc

// fp32 -> bf16 bits, round-to-nearest-even
__device__ __forceinline__ u16 f2b(float f) {
    union { float f; unsigned int u; } x; x.f = f;
    unsigned int r = x.u + 0x7FFFu + ((x.u >> 16) & 1u);
    return (u16)(r >> 16);
}

// ---------------------------------------------------------------------------
// adjpack: adj (128 MB int) -> 1-bit mask (4 MB), bit j of word = adj[row,j]>0.
// mask u64 layout: mask64[row*32 + j/64] — linear in segment index s.
// Per-CU-pipe model (R7): every byte of adj dragged through a CU's L1 during
// the attn loop costs ~1/10 B/cy; packing 32:1 in a dedicated streaming pass
// (chip HBM-bound, ~20 us) removes adj from attn's per-CU byte budget AND
// stops the 128 MB stream from thrashing the B-panels out of per-XCD L2.
// Nontemporal loads: adj is read exactly once, don't allocate in L2/L3.
// ---------------------------------------------------------------------------
__global__ __launch_bounds__(256) void adjpack(const int* __restrict__ adj,
                                               u64* __restrict__ mask)
{
    const int wid  = (blockIdx.x * 256 + threadIdx.x) >> 6;   // 8192 waves
    const int lane = threadIdx.x & 63;
    // 8*2048*2048/64 = 524288 segments of 64 ints; 64 iters/wave
#pragma unroll 4
    for (int it = 0; it < 64; ++it) {
        const long s = (long)it * 8192 + wid;
        const int v = __builtin_nontemporal_load(adj + s * 64 + lane);
        const u64 m = __ballot(v > 0);
        if (lane == 0) mask[s] = m;
    }
}

// ---------------------------------------------------------------------------
// prep: fused transposes + calc_v (G13-vectorized, proven in R7).
// ---------------------------------------------------------------------------
__device__ __forceinline__ void transp_body4(const float* __restrict__ src,
                                             u16* __restrict__ dst,
                                             int R, int C, int tid,
                                             float (*tile)[33])
{
    const int per = (R / 32) * (C / 32);
    const int b  = tid / per;
    const int tt = tid % per;
    const int jt = tt / (C / 32);
    const int ct = tt % (C / 32);
    src += (long)b * R * C;
    dst += (long)b * R * C;

    const int t = threadIdx.x;
    const int lr = t >> 3, lc = (t & 7) * 4;
    float4 v = *(const float4*)(src + (long)(jt * 32 + lr) * C + ct * 32 + lc);
    tile[lr][lc + 0] = v.x;
    tile[lr][lc + 1] = v.y;
    tile[lr][lc + 2] = v.z;
    tile[lr][lc + 3] = v.w;
    __syncthreads();
    const int c = t >> 3, r4 = (t & 7) * 4;
    ushort4 o;
    o.x = f2b(tile[r4 + 0][c]);
    o.y = f2b(tile[r4 + 1][c]);
    o.z = f2b(tile[r4 + 2][c]);
    o.w = f2b(tile[r4 + 3][c]);
    *(ushort4*)(dst + (long)(ct * 32 + c) * R + jt * 32 + r4) = o;
}

__global__ __launch_bounds__(256) void prep(const float* __restrict__ h,
                                            const float* __restrict__ g,
                                            const float* __restrict__ W1,
                                            const float* __restrict__ W2,
                                            const float* __restrict__ a,
                                            u16* __restrict__ HbfT,
                                            u16* __restrict__ GbfT,
                                            u16* __restrict__ W1T,
                                            u16* __restrict__ W2T,
                                            float* __restrict__ v1,
                                            float* __restrict__ v2)
{
    __shared__ float tile[32][33];
    __shared__ float s1[IN_F], s2[IN_F];
    const int bid = blockIdx.x;

    if (bid < 4096) {
        transp_body4(h, HbfT, NN, IN_F, bid, tile);
    } else if (bid < 8192) {
        transp_body4(g, GbfT, NN, IN_F, bid - 4096, tile);
    } else if (bid < 8256) {
        transp_body4(W1, W1T, IN_F, IN_F, bid - 8192, tile);
    } else if (bid < 8320) {
        transp_body4(W2, W2T, IN_F, IN_F, bid - 8256, tile);
    } else {
        const int t = threadIdx.x;
        s1[t] = a[t];
        s2[t] = a[IN_F + t];
        __syncthreads();
        float acc1 = 0.f, acc2 = 0.f;
        for (int c = 0; c < IN_F; ++c) {
            float w = W1[t * IN_F + c];
            acc1 += w * s1[c];
            acc2 += w * s2[c];
        }
        v1[t] = acc1;
        v2[t] = acc2;
    }
}

// ---------------------------------------------------------------------------
// rowdots: Wh1[row] = h[row,:]·v1, Wh2[row] = h[row,:]·v2. One wave per row.
// ---------------------------------------------------------------------------
__global__ __launch_bounds__(256) void rowdots(const float* __restrict__ h,
                                               const float* __restrict__ v1,
                                               const float* __restrict__ v2,
                                               float* __restrict__ Wh1,
                                               float* __restrict__ Wh2)
{
    const int wave = threadIdx.x >> 6;
    const int lane = threadIdx.x & 63;
    const long row = (long)blockIdx.x * 4 + wave;
    const int c0 = lane * 4;

    float4 v  = *(const float4*)(h + row * IN_F + c0);
    float4 a1 = *(const float4*)(v1 + c0);
    float4 a2 = *(const float4*)(v2 + c0);

    float s1 = v.x * a1.x + v.y * a1.y + v.z * a1.z + v.w * a1.w;
    float s2 = v.x * a2.x + v.y * a2.y + v.z * a2.z + v.w * a2.w;
#pragma unroll
    for (int off = 32; off; off >>= 1) {
        s1 += __shfl_xor(s1, off, 64);
        s2 += __shfl_xor(s2, off, 64);
    }
    if (lane == 0) { Wh1[row] = s1; Wh2[row] = s2; }
}

// ---------------------------------------------------------------------------
// attn_mfma v9: v3's exact loop schedule (101 us best), with the adj/w4
// traffic REMOVED per the per-CU byte model:
//   v3 bytes/block: B 2 MB (L3-rate, thrashed by adj stream) + adj 512 KB
//   (HBM rate) ~= 2.5 MB @ ~10 B/cy/CU = ~105 us  == measured 101 us.
// v9: adj -> premade bitmask (1 u32/thread/chunk, parity-reg prefetch);
// wh2 -> LDS (staged once).  In-loop global traffic = B panels + mask,
// all L2-resident per XCD (4 MB panel + 512 KB mask, no thrashing stream)
// -> ~60 B/cy/CU (m56).  Everything else (KSTEP, B ping-pong, lgkm-only
// barrier, A layout, epilogue) is v3 verbatim.
// ---------------------------------------------------------------------------
#define KSTEP(ksv, BC, BN_, AC, AN_, do_a, jnxt)                              \
    {                                                                         \
        if (do_a) {                                                           \
            _Pragma("unroll") for (int rt = 0; rt < 4; ++rt)                  \
                AN_[rt] = *(const short8x*)&ab[(((ksv) + 1) * 4 + rt) * 512 + lane * 8]; \
        }                                                                     \
        _Pragma("unroll") for (int ct = 0; ct < 4; ++ct)                      \
            BN_[ct] = *(const short8x*)(Bp + ct * 16 * NN + (jnxt));          \
        _Pragma("unroll") for (int rt = 0; rt < 4; ++rt)                      \
            _Pragma("unroll") for (int ct = 0; ct < 4; ++ct)                  \
                acc[rt][ct] = __builtin_amdgcn_mfma_f32_16x16x32_bf16(AC[rt], BC[ct], acc[rt][ct], 0, 0, 0); \
    }

#define CHUNK9(KCH, MKC, MKN)                                                 \
    {                                                                         \
        const int j0 = (KCH) * 128;                                           \
        const unsigned bits = (MKC) >> ((sg & 1) * 16);                       \
        union { short8x v; u16 e[8]; } pk0, pk1;                              \
        _Pragma("unroll") for (int u = 0; u < 4; ++u) {                       \
            const float4 wv = *(const float4*)&wh2L[j0 + sg * 16 + u * 4];    \
            const float wf[4] = {wv.x, wv.y, wv.z, wv.w};                     \
            _Pragma("unroll") for (int c = 0; c < 4; ++c) {                   \
                float x = wh1rr + wf[c];                                      \
                float ev = fmaxf(x, 0.2f * x);                                \
                float p = __expf(ev - mv);                                    \
                p = ((bits >> (u * 4 + c)) & 1u) ? p : 0.0f;                  \
                lloc += p;                                                    \
                u16 fv = f2b(p);                                              \
                if (u < 2) pk0.e[u * 4 + c] = fv;                             \
                else       pk1.e[(u - 2) * 4 + c] = fv;                       \
            }                                                                 \
        }                                                                     \
        if ((KCH) < 15) MKN = maskR[((KCH) + 1) * 4 + (sg >> 1)];             \
        u16* ab = &Afrag[(KCH) & 1][0];                                       \
        *(short8x*)&ab[wbase0]       = pk0.v;                                 \
        *(short8x*)&ab[wbase0 + 128] = pk1.v;                                 \
        asm volatile("s_waitcnt lgkmcnt(0)\n\ts_barrier" ::: "memory");       \
        _Pragma("unroll") for (int rt = 0; rt < 4; ++rt)                      \
            A0[rt] = *(const short8x*)&ab[rt * 512 + lane * 8];               \
        KSTEP(0, B0, B1, A0, A1, 1, j0 + 1 * 32 + bq8)                        \
        KSTEP(1, B1, B0, A1, A0, 1, j0 + 2 * 32 + bq8)                        \
        KSTEP(2, B0, B1, A0, A1, 1, j0 + 3 * 32 + bq8)                        \
        KSTEP(3, B1, B0, A1, A0, 0, (((KCH) < 15) ? (j0 + 128) : j0) + bq8)   \
    }

__global__ __launch_bounds__(512, 2) void attn_mfma(
    const unsigned* __restrict__ mask,
    const u16* __restrict__ HbfT, const u16* __restrict__ GbfT,
    const float* __restrict__ Wh1, const float* __restrict__ Wh2,
    u16* __restrict__ PH, u16* __restrict__ PG)
{
    const int t = threadIdx.x;
    const int wave = t >> 6, lane = t & 63;
    // batch-per-XCD swizzle: 256 blocks / 8 XCDs -> 32 blocks = 1 batch each
    const int bswz = ((blockIdx.x & 7) << 5) | (blockIdx.x >> 3);
    const int b = bswz >> 5;                  // 32 row-blocks per batch
    const long gi0 = (long)bswz * 64;         // global row base (BM=64)

    __shared__ __align__(16) u16 Afrag[2][8192];   // 2 x 16 KB (4 ksteps x 4 rt)
    __shared__ float wh2L[2048];                   // 8 KB: batch Wh2 slice
    __shared__ float sred[512];
    __shared__ float ssc[65];                      // [0..63]=1/l, [64]=wh2max

    // p-compute role: row rr (64 rows), segment sg (8) -> 16 consecutive j
    const int rr = t >> 3, sg = t & 7;
    const float* wh2b = Wh2 + (long)b * NN;
    const float wh1rr = Wh1[gi0 + rr];
    // per-thread mask row pointer (u32 words; word = kch*4 + sg/2)
    const unsigned* maskR = mask + (gi0 + rr) * 64;

    // ---- stage Wh2 slice to LDS + per-batch max ----
    {
        float4 w = *(const float4*)(wh2b + t * 4);
        *(float4*)&wh2L[t * 4] = w;
        sred[t] = fmaxf(fmaxf(w.x, w.y), fmaxf(w.z, w.w));
    }
    __syncthreads();
    if (t < 64) {
        float v = sred[t * 8];
#pragma unroll
        for (int k = 1; k < 8; ++k) v = fmaxf(v, sred[t * 8 + k]);
#pragma unroll
        for (int off = 32; off; off >>= 1) v = fmaxf(v, __shfl_xor(v, off, 64));
        if (t == 0) ssc[64] = v;
    }
    __syncthreads();
    const float mm = wh1rr + ssc[64];
    const float mv = (mm >= 0.f) ? mm : 0.2f * mm;   // lrelu upper bound >= all logits

    // A-fragment write slot (16x16x32 A layout: lane = m + 16*(k>>3), 8 k/lane)
    const int wbase0 = ((sg >> 1) * 4 + (rr >> 4)) * 512
                     + ((rr & 15) + 16 * (2 * (sg & 1))) * 8;

    float4x acc[4][4];
#pragma unroll
    for (int rt = 0; rt < 4; ++rt)
#pragma unroll
        for (int ct = 0; ct < 4; ++ct) acc[rt][ct] = (float4x)0.0f;

    const int bn = lane & 15, bq = lane >> 4, bq8 = bq * 8;
    const long hbase = (long)b * IN_F * NN;
    // wave -> matrix + 64-col slice: waves 0-3 = H cols, 4-7 = G cols
    const u16* Bp = ((wave < 4) ? HbfT : GbfT) + hbase
                  + (long)((wave & 3) * 64 + bn) * NN;

    float lloc = 0.f;

    short8x A0[4], A1[4], B0[4], B1[4];
    unsigned mkA, mkB;

    // ---- prologue: mask words for chunks 0 and 1; B group (kch=0, ks=0) ----
    mkA = maskR[sg >> 1];
    mkB = maskR[4 + (sg >> 1)];
#pragma unroll
    for (int ct = 0; ct < 4; ++ct)
        B0[ct] = *(const short8x*)(Bp + ct * 16 * NN + bq8);

    for (int kp = 0; kp < 8; ++kp) {
        CHUNK9(kp * 2,     mkA, mkB)
        CHUNK9(kp * 2 + 1, mkB, mkA)
    }

    // ---- reduce l per row (8 partials/row), invert ----
    sred[t] = lloc;
    __syncthreads();
    if (t < 64) {
        float v = sred[t * 8];
#pragma unroll
        for (int k = 1; k < 8; ++k) v += sred[t * 8 + k];
        ssc[t] = 1.0f / v;       // v > 0 always (~half the j's unmasked)
    }
    __syncthreads();

    // ---- scale by 1/l and store (C-layout: col=lane&15, row=(lane>>4)*4+reg)
    u16* dst = (wave < 4) ? PH : PG;
    const int colb = (wave & 3) * 64;
#pragma unroll
    for (int rt = 0; rt < 4; ++rt)
#pragma unroll
        for (int ct = 0; ct < 4; ++ct) {
            const int c = colb + ct * 16 + bn;
#pragma unroll
            for (int reg = 0; reg < 4; ++reg) {
                const int rl = rt * 16 + bq * 4 + reg;
                const float il = ssc[rl];
                const long row = gi0 + rl;
                dst[row * IN_F + c] = f2b(acc[rt][ct][reg] * il);
            }
        }
}

// ---------------------------------------------------------------------------
// epi2: both epilogue GEMMs in one launch.
// blocks [0,512): out0 = ELU(PH @ W1); blocks [512,1024): out1 = ELU(PG @ W2)
// ---------------------------------------------------------------------------
__global__ __launch_bounds__(256) void epi2(const u16* __restrict__ PH,
                                            const u16* __restrict__ PG,
                                            const u16* __restrict__ W1T,
                                            const u16* __restrict__ W2T,
                                            float* __restrict__ out)
{
    int bid = blockIdx.x;
    const u16* X;
    const u16* WT;
    float* o;
    if (bid < 512) { X = PH; WT = W1T; o = out; }
    else           { X = PG; WT = W2T; o = out + (long)BB * NN * IN_F; bid -= 512; }

    const int t = threadIdx.x;
    const int wave = t >> 6, lane = t & 63;
    const long i0 = (long)bid * 32;

    __shared__ __align__(16) u16 Afrag[8 * 2 * 64 * 8];   // 16 KB

    const int m = t >> 3, ks0 = t & 7, rt0 = m >> 4, lm = m & 15;
    const u16* xp = X + (i0 + m) * IN_F + ks0 * 32;
#pragma unroll
    for (int q = 0; q < 4; ++q) {
        short8x v = *(const short8x*)(xp + q * 8);
        *(short8x*)&Afrag[((ks0 * 2 + rt0) * 64 + lm + q * 16) * 8] = v;
    }
    __syncthreads();

    float4x acc[2][4];
#pragma unroll
    for (int rt = 0; rt < 2; ++rt)
#pragma unroll
        for (int ct = 0; ct < 4; ++ct) acc[rt][ct] = (float4x)0.0f;

    const int bn = lane & 15, bq = lane >> 4;
#pragma unroll
    for (int ks = 0; ks < 8; ++ks) {
        short8x A0 = *(const short8x*)&Afrag[((ks * 2 + 0) * 64 + lane) * 8];
        short8x A1 = *(const short8x*)&Afrag[((ks * 2 + 1) * 64 + lane) * 8];
#pragma unroll
        for (int ct = 0; ct < 4; ++ct) {
            const int n = wave * 64 + ct * 16 + bn;
            short8x Bw = *(const short8x*)(WT + n * IN_F + ks * 32 + bq * 8);
            acc[0][ct] = __builtin_amdgcn_mfma_f32_16x16x32_bf16(A0, Bw, acc[0][ct], 0, 0, 0);
            acc[1][ct] = __builtin_amdgcn_mfma_f32_16x16x32_bf16(A1, Bw, acc[1][ct], 0, 0, 0);
        }
    }

#pragma unroll
    for (int rt = 0; rt < 2; ++rt)
#pragma unroll
        for (int ct = 0; ct < 4; ++ct) {
            const int n = wave * 64 + ct * 16 + bn;
#pragma unroll
            for (int reg = 0; reg < 4; ++reg) {
                const long row = i0 + rt * 16 + bq * 4 + reg;
                float v = acc[rt][ct][reg];
                v = (v > 0.f) ? v : (__expf(v) - 1.f);   // ELU
                o[row * IN_F + n] = v;
            }
        }
}

// ---------------------------------------------------------------------------
extern "C" void kernel_launch(void* const* d_in, const int* in_sizes, int n_in,
                              void* d_out, int out_size, void* d_ws, size_t ws_size,
                              hipStream_t stream)
{
    int ih = -1, ig = -1, iadj = -1, iw1 = -1, iw2 = -1, ia = -1;
    for (int i = 0; i < n_in; ++i) {
        int s = in_sizes[i];
        if      (s == BB * NN * NN)   { if (iadj < 0) iadj = i; }
        else if (s == BB * NN * IN_F) { if (ih < 0) ih = i; else if (ig < 0) ig = i; }
        else if (s == IN_F * IN_F)    { if (iw1 < 0) iw1 = i; else if (iw2 < 0) iw2 = i; }
        else if (s == 2 * IN_F)       { if (ia < 0) ia = i; }
    }
    if (ih < 0 || ig < 0 || iadj < 0 || iw1 < 0 || iw2 < 0 || ia < 0) {
        ih = 0; iadj = 1; ig = 2; iw1 = 3; iw2 = 4; ia = 5;
    }
    const float* h     = (const float*)d_in[ih];
    const int*   adj   = (const int*)  d_in[iadj];
    const float* lrgt1 = (const float*)d_in[ig];
    const float* W1    = (const float*)d_in[iw1];
    const float* W2    = (const float*)d_in[iw2];
    const float* a     = (const float*)d_in[ia];
    float* out = (float*)d_out;

    // adj bitmask (4 MB) lives in the FIRST 4 MB of d_out — scratch until
    // epi2 (stream-ordered after attn) overwrites the full output.
    u64*      mask64 = (u64*)d_out;
    unsigned* mask32 = (unsigned*)d_out;

    // ws layout — 33,949,696 B total (<= proven-available 34,212,096 B)
    float* ws   = (float*)d_ws;
    float* v1   = ws;                       // 256
    float* v2   = v1 + IN_F;                // 256
    float* Wh1  = v2 + IN_F;                // 16384
    float* Wh2  = Wh1 + BB * NN;            // 16384
    u16* W1T  = (u16*)(Wh2 + BB * NN);      // 65536 bf16
    u16* W2T  = W1T + IN_F * IN_F;          // 65536
    u16* HbfT = W2T + IN_F * IN_F;          // 8*256*2048
    u16* GbfT = HbfT + (long)BB * IN_F * NN;
    u16* PH   = GbfT + (long)BB * IN_F * NN;
    u16* PG   = PH + (long)BB * NN * IN_F;

    const int nrows = BB * NN;

    adjpack  <<<2048,        256, 0, stream>>>(adj, mask64);
    prep     <<<8321,        256, 0, stream>>>(h, lrgt1, W1, W2, a,
                                               HbfT, GbfT, W1T, W2T, v1, v2);
    rowdots  <<<nrows / 4,   256, 0, stream>>>(h, v1, v2, Wh1, Wh2);
    attn_mfma<<<nrows / 64,  512, 0, stream>>>(mask32, HbfT, GbfT, Wh1, Wh2, PH, PG);
    epi2     <<<2 * nrows / 32, 256, 0, stream>>>(PH, PG, W1T, W2T, out);
}

// Round 9
// 335.921 us; speedup vs baseline: 1.1346x; 1.0250x over previous
//
#include <hip/hip_runtime.h>
#include <hip/hip_bf16.h>

#define IN_F 256
#define NN   2048
#define BB   8

typedef unsigned short u16;
typedef unsigned long long u64;
typedef __attribute__((ext_vector_type(8))) short short8x;   // 8 bf16 = 4 VGPRs
typedef __attribute__((ext_vector_type(4))) float float4x;   // MFMA acc

// fp32 -> bf16 bits, round-to-nearest-even
__device__ __forceinline__ u16 f2b(float f) {
    union { float f; unsigned int u; } x; x.f = f;
    unsigned int r = x.u + 0x7FFFu + ((x.u >> 16) & 1u);
    return (u16)(r >> 16);
}

// ---------------------------------------------------------------------------
// adjpack: adj (128 MB int) -> 1-bit mask (4 MB).  (R8-proven: removed adj
// from attn's per-CU byte budget; FETCH 74->10 MB.)
// ---------------------------------------------------------------------------
__global__ __launch_bounds__(256) void adjpack(const int* __restrict__ adj,
                                               u64* __restrict__ mask)
{
    const int wid  = (blockIdx.x * 256 + threadIdx.x) >> 6;   // 8192 waves
    const int lane = threadIdx.x & 63;
#pragma unroll 4
    for (int it = 0; it < 64; ++it) {
        const long s = (long)it * 8192 + wid;
        const int v = __builtin_nontemporal_load(adj + s * 64 + lane);
        const u64 m = __ballot(v > 0);
        if (lane == 0) mask[s] = m;
    }
}

// ---------------------------------------------------------------------------
// prep: fused transposes + calc_v (G13-vectorized).
// ---------------------------------------------------------------------------
__device__ __forceinline__ void transp_body4(const float* __restrict__ src,
                                             u16* __restrict__ dst,
                                             int R, int C, int tid,
                                             float (*tile)[33])
{
    const int per = (R / 32) * (C / 32);
    const int b  = tid / per;
    const int tt = tid % per;
    const int jt = tt / (C / 32);
    const int ct = tt % (C / 32);
    src += (long)b * R * C;
    dst += (long)b * R * C;

    const int t = threadIdx.x;
    const int lr = t >> 3, lc = (t & 7) * 4;
    float4 v = *(const float4*)(src + (long)(jt * 32 + lr) * C + ct * 32 + lc);
    tile[lr][lc + 0] = v.x;
    tile[lr][lc + 1] = v.y;
    tile[lr][lc + 2] = v.z;
    tile[lr][lc + 3] = v.w;
    __syncthreads();
    const int c = t >> 3, r4 = (t & 7) * 4;
    ushort4 o;
    o.x = f2b(tile[r4 + 0][c]);
    o.y = f2b(tile[r4 + 1][c]);
    o.z = f2b(tile[r4 + 2][c]);
    o.w = f2b(tile[r4 + 3][c]);
    *(ushort4*)(dst + (long)(ct * 32 + c) * R + jt * 32 + r4) = o;
}

__global__ __launch_bounds__(256) void prep(const float* __restrict__ h,
                                            const float* __restrict__ g,
                                            const float* __restrict__ W1,
                                            const float* __restrict__ W2,
                                            const float* __restrict__ a,
                                            u16* __restrict__ HbfT,
                                            u16* __restrict__ GbfT,
                                            u16* __restrict__ W1T,
                                            u16* __restrict__ W2T,
                                            float* __restrict__ v1,
                                            float* __restrict__ v2)
{
    __shared__ float tile[32][33];
    __shared__ float s1[IN_F], s2[IN_F];
    const int bid = blockIdx.x;

    if (bid < 4096) {
        transp_body4(h, HbfT, NN, IN_F, bid, tile);
    } else if (bid < 8192) {
        transp_body4(g, GbfT, NN, IN_F, bid - 4096, tile);
    } else if (bid < 8256) {
        transp_body4(W1, W1T, IN_F, IN_F, bid - 8192, tile);
    } else if (bid < 8320) {
        transp_body4(W2, W2T, IN_F, IN_F, bid - 8256, tile);
    } else {
        const int t = threadIdx.x;
        s1[t] = a[t];
        s2[t] = a[IN_F + t];
        __syncthreads();
        float acc1 = 0.f, acc2 = 0.f;
        for (int c = 0; c < IN_F; ++c) {
            float w = W1[t * IN_F + c];
            acc1 += w * s1[c];
            acc2 += w * s2[c];
        }
        v1[t] = acc1;
        v2[t] = acc2;
    }
}

// ---------------------------------------------------------------------------
// rowdots: Wh1[row] = h[row,:]·v1, Wh2[row] = h[row,:]·v2. One wave per row.
// ---------------------------------------------------------------------------
__global__ __launch_bounds__(256) void rowdots(const float* __restrict__ h,
                                               const float* __restrict__ v1,
                                               const float* __restrict__ v2,
                                               float* __restrict__ Wh1,
                                               float* __restrict__ Wh2)
{
    const int wave = threadIdx.x >> 6;
    const int lane = threadIdx.x & 63;
    const long row = (long)blockIdx.x * 4 + wave;
    const int c0 = lane * 4;

    float4 v  = *(const float4*)(h + row * IN_F + c0);
    float4 a1 = *(const float4*)(v1 + c0);
    float4 a2 = *(const float4*)(v2 + c0);

    float s1 = v.x * a1.x + v.y * a1.y + v.z * a1.z + v.w * a1.w;
    float s2 = v.x * a2.x + v.y * a2.y + v.z * a2.z + v.w * a2.w;
#pragma unroll
    for (int off = 32; off; off >>= 1) {
        s1 += __shfl_xor(s1, off, 64);
        s2 += __shfl_xor(s2, off, 64);
    }
    if (lane == 0) { Wh1[row] = s1; Wh2[row] = s2; }
}

// ---------------------------------------------------------------------------
// attn_mfma v10: v9 (80.6 us, FETCH 10 MB) + full-chunk B prefetch depth-4.
// Remaining stall in v9: B ping-pong depth-1 covers only one kstep's MFMA
// phase (~80 cy) of the ~300-400 cy L2 latency -> ~300 cy exposed per kstep.
// Depth-4 (G0..G3, each group reissued right after its consumption, used
// again one full chunk later) gives ~1200+ cy cover.  This is v5's schedule
// WITHOUT v5's spill source: the 64 VGPRs of adj/w4 double-buffers are gone
// (mask words replaced them in v9).  Est ~185 VGPR <= 256 cap at (512,2).
// Tripwires: WRITE_SIZE ~16.4 MB (no spill), FETCH ~10.4 MB.
// ---------------------------------------------------------------------------
#define AREAD(AR, KS)                                                         \
    _Pragma("unroll") for (int rt = 0; rt < 4; ++rt)                          \
        AR[rt] = *(const short8x*)&ab[((KS) * 4 + rt) * 512 + lane * 8];

#define MFMA16(AR, G)                                                         \
    _Pragma("unroll") for (int rt = 0; rt < 4; ++rt)                          \
        _Pragma("unroll") for (int ct = 0; ct < 4; ++ct)                      \
            acc[rt][ct] = __builtin_amdgcn_mfma_f32_16x16x32_bf16(AR[rt], G[ct], acc[rt][ct], 0, 0, 0);

#define BISSUE(G, KN, KS)                                                     \
    _Pragma("unroll") for (int ct = 0; ct < 4; ++ct)                          \
        G[ct] = *(const short8x*)(Bp + ct * 16 * NN + ((KN) * 128 + (KS) * 32 + bq8));

#define CHUNK10(KCH, MKC, MKN)                                                \
    {                                                                         \
        const int j0 = (KCH) * 128;                                           \
        const unsigned bits = (MKC) >> ((sg & 1) * 16);                       \
        union { short8x v; u16 e[8]; } pk0, pk1;                              \
        _Pragma("unroll") for (int u = 0; u < 4; ++u) {                       \
            const float4 wv = *(const float4*)&wh2L[j0 + sg * 16 + u * 4];    \
            const float wf[4] = {wv.x, wv.y, wv.z, wv.w};                     \
            _Pragma("unroll") for (int c = 0; c < 4; ++c) {                   \
                float x = wh1rr + wf[c];                                      \
                float ev = fmaxf(x, 0.2f * x);                                \
                float p = __expf(ev - mv);                                    \
                p = ((bits >> (u * 4 + c)) & 1u) ? p : 0.0f;                  \
                lloc += p;                                                    \
                u16 fv = f2b(p);                                              \
                if (u < 2) pk0.e[u * 4 + c] = fv;                             \
                else       pk1.e[(u - 2) * 4 + c] = fv;                       \
            }                                                                 \
        }                                                                     \
        if ((KCH) < 15) MKN = maskR[((KCH) + 1) * 4 + (sg >> 1)];             \
        u16* ab = &Afrag[(KCH) & 1][0];                                       \
        *(short8x*)&ab[wbase0]       = pk0.v;                                 \
        *(short8x*)&ab[wbase0 + 128] = pk1.v;                                 \
        asm volatile("s_waitcnt lgkmcnt(0)\n\ts_barrier" ::: "memory");       \
        AREAD(Aa, 0)                                                          \
        AREAD(Ab, 1)                                                          \
        MFMA16(Aa, G0)                                                        \
        if ((KCH) < 15) { BISSUE(G0, (KCH) + 1, 0) }                          \
        AREAD(Aa, 2)                                                          \
        MFMA16(Ab, G1)                                                        \
        if ((KCH) < 15) { BISSUE(G1, (KCH) + 1, 1) }                          \
        AREAD(Ab, 3)                                                          \
        MFMA16(Aa, G2)                                                        \
        if ((KCH) < 15) { BISSUE(G2, (KCH) + 1, 2) }                          \
        MFMA16(Ab, G3)                                                        \
        if ((KCH) < 15) { BISSUE(G3, (KCH) + 1, 3) }                          \
    }

__global__ __launch_bounds__(512, 2) void attn_mfma(
    const unsigned* __restrict__ mask,
    const u16* __restrict__ HbfT, const u16* __restrict__ GbfT,
    const float* __restrict__ Wh1, const float* __restrict__ Wh2,
    u16* __restrict__ PH, u16* __restrict__ PG)
{
    const int t = threadIdx.x;
    const int wave = t >> 6, lane = t & 63;
    // batch-per-XCD swizzle: 256 blocks / 8 XCDs -> 32 blocks = 1 batch each
    const int bswz = ((blockIdx.x & 7) << 5) | (blockIdx.x >> 3);
    const int b = bswz >> 5;                  // 32 row-blocks per batch
    const long gi0 = (long)bswz * 64;         // global row base (BM=64)

    __shared__ __align__(16) u16 Afrag[2][8192];   // 2 x 16 KB (4 ksteps x 4 rt)
    __shared__ float wh2L[2048];                   // 8 KB: batch Wh2 slice
    __shared__ float sred[512];
    __shared__ float ssc[65];                      // [0..63]=1/l, [64]=wh2max

    // p-compute role: row rr (64 rows), segment sg (8) -> 16 consecutive j
    const int rr = t >> 3, sg = t & 7;
    const float* wh2b = Wh2 + (long)b * NN;
    const float wh1rr = Wh1[gi0 + rr];
    // per-thread mask row pointer (u32 words; word = kch*4 + sg/2)
    const unsigned* maskR = mask + (gi0 + rr) * 64;

    // ---- stage Wh2 slice to LDS + per-batch max ----
    {
        float4 w = *(const float4*)(wh2b + t * 4);
        *(float4*)&wh2L[t * 4] = w;
        sred[t] = fmaxf(fmaxf(w.x, w.y), fmaxf(w.z, w.w));
    }
    __syncthreads();
    if (t < 64) {
        float v = sred[t * 8];
#pragma unroll
        for (int k = 1; k < 8; ++k) v = fmaxf(v, sred[t * 8 + k]);
#pragma unroll
        for (int off = 32; off; off >>= 1) v = fmaxf(v, __shfl_xor(v, off, 64));
        if (t == 0) ssc[64] = v;
    }
    __syncthreads();
    const float mm = wh1rr + ssc[64];
    const float mv = (mm >= 0.f) ? mm : 0.2f * mm;   // lrelu upper bound >= all logits

    // A-fragment write slot (16x16x32 A layout: lane = m + 16*(k>>3), 8 k/lane)
    const int wbase0 = ((sg >> 1) * 4 + (rr >> 4)) * 512
                     + ((rr & 15) + 16 * (2 * (sg & 1))) * 8;

    float4x acc[4][4];
#pragma unroll
    for (int rt = 0; rt < 4; ++rt)
#pragma unroll
        for (int ct = 0; ct < 4; ++ct) acc[rt][ct] = (float4x)0.0f;

    const int bn = lane & 15, bq = lane >> 4, bq8 = bq * 8;
    const long hbase = (long)b * IN_F * NN;
    // wave -> matrix + 64-col slice: waves 0-3 = H cols, 4-7 = G cols
    const u16* Bp = ((wave < 4) ? HbfT : GbfT) + hbase
                  + (long)((wave & 3) * 64 + bn) * NN;

    float lloc = 0.f;

    short8x Aa[4], Ab[4];
    short8x G0[4], G1[4], G2[4], G3[4];
    unsigned mkA, mkB;

    // ---- prologue: mask words chunks 0/1; all 4 B groups of chunk 0 ----
    mkA = maskR[sg >> 1];
    mkB = maskR[4 + (sg >> 1)];
    BISSUE(G0, 0, 0)
    BISSUE(G1, 0, 1)
    BISSUE(G2, 0, 2)
    BISSUE(G3, 0, 3)

    for (int kp = 0; kp < 8; ++kp) {
        CHUNK10(kp * 2,     mkA, mkB)
        CHUNK10(kp * 2 + 1, mkB, mkA)
    }

    // ---- reduce l per row (8 partials/row), invert ----
    sred[t] = lloc;
    __syncthreads();
    if (t < 64) {
        float v = sred[t * 8];
#pragma unroll
        for (int k = 1; k < 8; ++k) v += sred[t * 8 + k];
        ssc[t] = 1.0f / v;       // v > 0 always (~half the j's unmasked)
    }
    __syncthreads();

    // ---- scale by 1/l and store (C-layout: col=lane&15, row=(lane>>4)*4+reg)
    u16* dst = (wave < 4) ? PH : PG;
    const int colb = (wave & 3) * 64;
#pragma unroll
    for (int rt = 0; rt < 4; ++rt)
#pragma unroll
        for (int ct = 0; ct < 4; ++ct) {
            const int c = colb + ct * 16 + bn;
#pragma unroll
            for (int reg = 0; reg < 4; ++reg) {
                const int rl = rt * 16 + bq * 4 + reg;
                const float il = ssc[rl];
                const long row = gi0 + rl;
                dst[row * IN_F + c] = f2b(acc[rt][ct][reg] * il);
            }
        }
}

// ---------------------------------------------------------------------------
// epi2: both epilogue GEMMs in one launch, Bw depth-1 ping-pong prefetch
// (was: Bw loaded immediately before the consuming MFMA — zero cover).
// ---------------------------------------------------------------------------
#define EPIK(KS, BC, BN_)                                                     \
    {                                                                         \
        if ((KS) < 7) {                                                       \
            _Pragma("unroll") for (int ct = 0; ct < 4; ++ct)                  \
                BN_[ct] = *(const short8x*)(WTrow + ct * 16 * IN_F + ((KS) + 1) * 32 + bq8); \
        }                                                                     \
        short8x A0 = *(const short8x*)&Afrag[(((KS) * 2 + 0) * 64 + lane) * 8]; \
        short8x A1 = *(const short8x*)&Afrag[(((KS) * 2 + 1) * 64 + lane) * 8]; \
        _Pragma("unroll") for (int ct = 0; ct < 4; ++ct) {                    \
            acc[0][ct] = __builtin_amdgcn_mfma_f32_16x16x32_bf16(A0, BC[ct], acc[0][ct], 0, 0, 0); \
            acc[1][ct] = __builtin_amdgcn_mfma_f32_16x16x32_bf16(A1, BC[ct], acc[1][ct], 0, 0, 0); \
        }                                                                     \
    }

__global__ __launch_bounds__(256) void epi2(const u16* __restrict__ PH,
                                            const u16* __restrict__ PG,
                                            const u16* __restrict__ W1T,
                                            const u16* __restrict__ W2T,
                                            float* __restrict__ out)
{
    int bid = blockIdx.x;
    const u16* X;
    const u16* WT;
    float* o;
    if (bid < 512) { X = PH; WT = W1T; o = out; }
    else           { X = PG; WT = W2T; o = out + (long)BB * NN * IN_F; bid -= 512; }

    const int t = threadIdx.x;
    const int wave = t >> 6, lane = t & 63;
    const long i0 = (long)bid * 32;

    __shared__ __align__(16) u16 Afrag[8 * 2 * 64 * 8];   // 16 KB

    const int m = t >> 3, ks0 = t & 7, rt0 = m >> 4, lm = m & 15;
    const u16* xp = X + (i0 + m) * IN_F + ks0 * 32;
#pragma unroll
    for (int q = 0; q < 4; ++q) {
        short8x v = *(const short8x*)(xp + q * 8);
        *(short8x*)&Afrag[((ks0 * 2 + rt0) * 64 + lm + q * 16) * 8] = v;
    }

    const int bn = lane & 15, bq = lane >> 4, bq8 = bq * 8;
    const u16* WTrow = WT + (long)(wave * 64 + bn) * IN_F;

    float4x acc[2][4];
#pragma unroll
    for (int rt = 0; rt < 2; ++rt)
#pragma unroll
        for (int ct = 0; ct < 4; ++ct) acc[rt][ct] = (float4x)0.0f;

    short8x BwA[4], BwB[4];
#pragma unroll
    for (int ct = 0; ct < 4; ++ct)
        BwA[ct] = *(const short8x*)(WTrow + ct * 16 * IN_F + bq8);

    __syncthreads();

#pragma unroll
    for (int kp2 = 0; kp2 < 4; ++kp2) {
        EPIK(kp2 * 2,     BwA, BwB)
        EPIK(kp2 * 2 + 1, BwB, BwA)
    }

#pragma unroll
    for (int rt = 0; rt < 2; ++rt)
#pragma unroll
        for (int ct = 0; ct < 4; ++ct) {
            const int n = wave * 64 + ct * 16 + bn;
#pragma unroll
            for (int reg = 0; reg < 4; ++reg) {
                const long row = i0 + rt * 16 + bq * 4 + reg;
                float v = acc[rt][ct][reg];
                v = (v > 0.f) ? v : (__expf(v) - 1.f);   // ELU
                o[row * IN_F + n] = v;
            }
        }
}

// ---------------------------------------------------------------------------
extern "C" void kernel_launch(void* const* d_in, const int* in_sizes, int n_in,
                              void* d_out, int out_size, void* d_ws, size_t ws_size,
                              hipStream_t stream)
{
    int ih = -1, ig = -1, iadj = -1, iw1 = -1, iw2 = -1, ia = -1;
    for (int i = 0; i < n_in; ++i) {
        int s = in_sizes[i];
        if      (s == BB * NN * NN)   { if (iadj < 0) iadj = i; }
        else if (s == BB * NN * IN_F) { if (ih < 0) ih = i; else if (ig < 0) ig = i; }
        else if (s == IN_F * IN_F)    { if (iw1 < 0) iw1 = i; else if (iw2 < 0) iw2 = i; }
        else if (s == 2 * IN_F)       { if (ia < 0) ia = i; }
    }
    if (ih < 0 || ig < 0 || iadj < 0 || iw1 < 0 || iw2 < 0 || ia < 0) {
        ih = 0; iadj = 1; ig = 2; iw1 = 3; iw2 = 4; ia = 5;
    }
    const float* h     = (const float*)d_in[ih];
    const int*   adj   = (const int*)  d_in[iadj];
    const float* lrgt1 = (const float*)d_in[ig];
    const float* W1    = (const float*)d_in[iw1];
    const float* W2    = (const float*)d_in[iw2];
    const float* a     = (const float*)d_in[ia];
    float* out = (float*)d_out;

    // adj bitmask (4 MB) lives in the FIRST 4 MB of d_out — scratch until
    // epi2 (stream-ordered after attn) overwrites the full output.
    u64*      mask64 = (u64*)d_out;
    unsigned* mask32 = (unsigned*)d_out;

    // ws layout — 33,949,696 B total (<= proven-available 34,212,096 B)
    float* ws   = (float*)d_ws;
    float* v1   = ws;                       // 256
    float* v2   = v1 + IN_F;                // 256
    float* Wh1  = v2 + IN_F;                // 16384
    float* Wh2  = Wh1 + BB * NN;            // 16384
    u16* W1T  = (u16*)(Wh2 + BB * NN);      // 65536 bf16
    u16* W2T  = W1T + IN_F * IN_F;          // 65536
    u16* HbfT = W2T + IN_F * IN_F;          // 8*256*2048
    u16* GbfT = HbfT + (long)BB * IN_F * NN;
    u16* PH   = GbfT + (long)BB * IN_F * NN;
    u16* PG   = PH + (long)BB * NN * IN_F;

    const int nrows = BB * NN;

    adjpack  <<<2048,        256, 0, stream>>>(adj, mask64);
    prep     <<<8321,        256, 0, stream>>>(h, lrgt1, W1, W2, a,
                                               HbfT, GbfT, W1T, W2T, v1, v2);
    rowdots  <<<nrows / 4,   256, 0, stream>>>(h, v1, v2, Wh1, Wh2);
    attn_mfma<<<nrows / 64,  512, 0, stream>>>(mask32, HbfT, GbfT, Wh1, Wh2, PH, PG);
    epi2     <<<2 * nrows / 32, 256, 0, stream>>>(PH, PG, W1T, W2T, out);
}

// Round 10
// 323.646 us; speedup vs baseline: 1.1777x; 1.0379x over previous
//
#include <hip/hip_runtime.h>
#include <hip/hip_bf16.h>

#define IN_F 256
#define NN   2048
#define BB   8

typedef unsigned short u16;
typedef unsigned long long u64;
typedef __attribute__((ext_vector_type(8))) short short8x;   // 8 bf16 = 4 VGPRs
typedef __attribute__((ext_vector_type(4))) float float4x;   // MFMA acc

// fp32 -> bf16 bits, round-to-nearest-even
__device__ __forceinline__ u16 f2b(float f) {
    union { float f; unsigned int u; } x; x.f = f;
    unsigned int r = x.u + 0x7FFFu + ((x.u >> 16) & 1u);
    return (u16)(r >> 16);
}

// ---------------------------------------------------------------------------
// prep: fused transposes + calc_v (G13-vectorized).
// ---------------------------------------------------------------------------
__device__ __forceinline__ void transp_body4(const float* __restrict__ src,
                                             u16* __restrict__ dst,
                                             int R, int C, int tid,
                                             float (*tile)[33])
{
    const int per = (R / 32) * (C / 32);
    const int b  = tid / per;
    const int tt = tid % per;
    const int jt = tt / (C / 32);
    const int ct = tt % (C / 32);
    src += (long)b * R * C;
    dst += (long)b * R * C;

    const int t = threadIdx.x;
    const int lr = t >> 3, lc = (t & 7) * 4;
    float4 v = *(const float4*)(src + (long)(jt * 32 + lr) * C + ct * 32 + lc);
    tile[lr][lc + 0] = v.x;
    tile[lr][lc + 1] = v.y;
    tile[lr][lc + 2] = v.z;
    tile[lr][lc + 3] = v.w;
    __syncthreads();
    const int c = t >> 3, r4 = (t & 7) * 4;
    ushort4 o;
    o.x = f2b(tile[r4 + 0][c]);
    o.y = f2b(tile[r4 + 1][c]);
    o.z = f2b(tile[r4 + 2][c]);
    o.w = f2b(tile[r4 + 3][c]);
    *(ushort4*)(dst + (long)(ct * 32 + c) * R + jt * 32 + r4) = o;
}

__global__ __launch_bounds__(256) void prep(const float* __restrict__ h,
                                            const float* __restrict__ g,
                                            const float* __restrict__ W1,
                                            const float* __restrict__ W2,
                                            const float* __restrict__ a,
                                            u16* __restrict__ HbfT,
                                            u16* __restrict__ GbfT,
                                            u16* __restrict__ W1T,
                                            u16* __restrict__ W2T,
                                            float* __restrict__ v1,
                                            float* __restrict__ v2)
{
    __shared__ float tile[32][33];
    __shared__ float s1[IN_F], s2[IN_F];
    const int bid = blockIdx.x;

    if (bid < 4096) {
        transp_body4(h, HbfT, NN, IN_F, bid, tile);
    } else if (bid < 8192) {
        transp_body4(g, GbfT, NN, IN_F, bid - 4096, tile);
    } else if (bid < 8256) {
        transp_body4(W1, W1T, IN_F, IN_F, bid - 8192, tile);
    } else if (bid < 8320) {
        transp_body4(W2, W2T, IN_F, IN_F, bid - 8256, tile);
    } else {
        const int t = threadIdx.x;
        s1[t] = a[t];
        s2[t] = a[IN_F + t];
        __syncthreads();
        float acc1 = 0.f, acc2 = 0.f;
        for (int c = 0; c < IN_F; ++c) {
            float w = W1[t * IN_F + c];
            acc1 += w * s1[c];
            acc2 += w * s2[c];
        }
        v1[t] = acc1;
        v2[t] = acc2;
    }
}

// ---------------------------------------------------------------------------
// rowdots: Wh1[row] = h[row,:]·v1, Wh2[row] = h[row,:]·v2. One wave per row.
// ---------------------------------------------------------------------------
__global__ __launch_bounds__(256) void rowdots(const float* __restrict__ h,
                                               const float* __restrict__ v1,
                                               const float* __restrict__ v2,
                                               float* __restrict__ Wh1,
                                               float* __restrict__ Wh2)
{
    const int wave = threadIdx.x >> 6;
    const int lane = threadIdx.x & 63;
    const long row = (long)blockIdx.x * 4 + wave;
    const int c0 = lane * 4;

    float4 v  = *(const float4*)(h + row * IN_F + c0);
    float4 a1 = *(const float4*)(v1 + c0);
    float4 a2 = *(const float4*)(v2 + c0);

    float s1 = v.x * a1.x + v.y * a1.y + v.z * a1.z + v.w * a1.w;
    float s2 = v.x * a2.x + v.y * a2.y + v.z * a2.z + v.w * a2.w;
#pragma unroll
    for (int off = 32; off; off >>= 1) {
        s1 += __shfl_xor(s1, off, 64);
        s2 += __shfl_xor(s2, off, 64);
    }
    if (lane == 0) { Wh1[row] = s1; Wh2[row] = s2; }
}

// ---------------------------------------------------------------------------
// attn_mfma v11: v10 loop (depth-4 B prefetch, proven) + FUSED adj packing.
// R9 accounting: standalone adjpack cost ~45-50 us (scalar 4B/lane loads,
// G13 violation) + a launch boundary + 4 MB mask HBM round-trip.  v11:
// each block packs its OWN 64 adj rows (512 KB, contiguous) into a 16 KB
// LDS u16-mask in the prologue — 4x int4 loads/thread (64 B/thread).
// Chip-wide the same 128 MB adj stream now runs at vectorized HBM rate
// (~20 us) hidden inside attn instead of ~45-50 us standalone.  In-loop
// mask reads come from LDS (register-prefetched one chunk ahead, parity
// ping-pong — same structure as v10's mkA/mkB, source changed).
// LDS: 32K Afrag + 8K wh2 + 16K mask + 2K sred + ssc = 59.7 KB.
// Tripwires: WRITE ~16.4 MB (no spill), VGPR ~96-110.
// ---------------------------------------------------------------------------
#define AREAD(AR, KS)                                                         \
    _Pragma("unroll") for (int rt = 0; rt < 4; ++rt)                          \
        AR[rt] = *(const short8x*)&ab[((KS) * 4 + rt) * 512 + lane * 8];

#define MFMA16(AR, G)                                                         \
    _Pragma("unroll") for (int rt = 0; rt < 4; ++rt)                          \
        _Pragma("unroll") for (int ct = 0; ct < 4; ++ct)                      \
            acc[rt][ct] = __builtin_amdgcn_mfma_f32_16x16x32_bf16(AR[rt], G[ct], acc[rt][ct], 0, 0, 0);

#define BISSUE(G, KN, KS)                                                     \
    _Pragma("unroll") for (int ct = 0; ct < 4; ++ct)                          \
        G[ct] = *(const short8x*)(Bp + ct * 16 * NN + ((KN) * 128 + (KS) * 32 + bq8));

#define CHUNK11(KCH, MKC, MKN)                                                \
    {                                                                         \
        const int j0 = (KCH) * 128;                                           \
        const unsigned bits = (MKC);                                          \
        union { short8x v; u16 e[8]; } pk0, pk1;                              \
        _Pragma("unroll") for (int u = 0; u < 4; ++u) {                       \
            const float4 wv = *(const float4*)&wh2L[j0 + sg * 16 + u * 4];    \
            const float wf[4] = {wv.x, wv.y, wv.z, wv.w};                     \
            _Pragma("unroll") for (int c = 0; c < 4; ++c) {                   \
                float x = wh1rr + wf[c];                                      \
                float ev = fmaxf(x, 0.2f * x);                                \
                float p = __expf(ev - mv);                                    \
                p = ((bits >> (u * 4 + c)) & 1u) ? p : 0.0f;                  \
                lloc += p;                                                    \
                u16 fv = f2b(p);                                              \
                if (u < 2) pk0.e[u * 4 + c] = fv;                             \
                else       pk1.e[(u - 2) * 4 + c] = fv;                       \
            }                                                                 \
        }                                                                     \
        if ((KCH) < 15) MKN = maskL[mrow + ((KCH) + 1) * 8 + sg];             \
        u16* ab = &Afrag[(KCH) & 1][0];                                       \
        *(short8x*)&ab[wbase0]       = pk0.v;                                 \
        *(short8x*)&ab[wbase0 + 128] = pk1.v;                                 \
        asm volatile("s_waitcnt lgkmcnt(0)\n\ts_barrier" ::: "memory");       \
        AREAD(Aa, 0)                                                          \
        AREAD(Ab, 1)                                                          \
        MFMA16(Aa, G0)                                                        \
        if ((KCH) < 15) { BISSUE(G0, (KCH) + 1, 0) }                          \
        AREAD(Aa, 2)                                                          \
        MFMA16(Ab, G1)                                                        \
        if ((KCH) < 15) { BISSUE(G1, (KCH) + 1, 1) }                          \
        AREAD(Ab, 3)                                                          \
        MFMA16(Aa, G2)                                                        \
        if ((KCH) < 15) { BISSUE(G2, (KCH) + 1, 2) }                          \
        MFMA16(Ab, G3)                                                        \
        if ((KCH) < 15) { BISSUE(G3, (KCH) + 1, 3) }                          \
    }

__global__ __launch_bounds__(512, 2) void attn_mfma(
    const int* __restrict__ adj,
    const u16* __restrict__ HbfT, const u16* __restrict__ GbfT,
    const float* __restrict__ Wh1, const float* __restrict__ Wh2,
    u16* __restrict__ PH, u16* __restrict__ PG)
{
    const int t = threadIdx.x;
    const int wave = t >> 6, lane = t & 63;
    // batch-per-XCD swizzle: 256 blocks / 8 XCDs -> 32 blocks = 1 batch each
    const int bswz = ((blockIdx.x & 7) << 5) | (blockIdx.x >> 3);
    const int b = bswz >> 5;                  // 32 row-blocks per batch
    const long gi0 = (long)bswz * 64;         // global row base (BM=64)

    __shared__ __align__(16) u16 Afrag[2][8192];   // 2 x 16 KB (4 ksteps x 4 rt)
    __shared__ float wh2L[2048];                   // 8 KB: batch Wh2 slice
    __shared__ u16 maskL[8192];                    // 16 KB: 64 rows x 128 seg16
    __shared__ float sred[512];
    __shared__ float ssc[65];                      // [0..63]=1/l, [64]=wh2max

    // p-compute role: row rr (64 rows), segment sg (8) -> 16 consecutive j
    const int rr = t >> 3, sg = t & 7;
    const float* wh2b = Wh2 + (long)b * NN;
    const float wh1rr = Wh1[gi0 + rr];
    const int mrow = rr * 128;

    // ---- stage Wh2 slice to LDS + per-batch max partials ----
    {
        float4 w = *(const float4*)(wh2b + t * 4);
        *(float4*)&wh2L[t * 4] = w;
        sred[t] = fmaxf(fmaxf(w.x, w.y), fmaxf(w.z, w.w));
    }

    // ---- fused adj pack: 64 rows x 2048 -> u16 masks in LDS ----
    // seg s = row*128 + j16 covers j in [j16*16, +16); thread does 16 segs
    // (4x int4 = 64 B contiguous per seg).  512 KB/block, streamed once.
    {
        const int* adjB = adj + gi0 * (long)NN;
#pragma unroll 4
        for (int it = 0; it < 16; ++it) {
            const int s = it * 512 + t;
            const int4* p4 = (const int4*)(adjB + (long)s * 16);
            const int4 v0 = p4[0];
            const int4 v1 = p4[1];
            const int4 v2 = p4[2];
            const int4 v3 = p4[3];
            unsigned m = 0;
            m |= ((unsigned)(v0.x > 0))       | ((unsigned)(v0.y > 0) << 1)
               | ((unsigned)(v0.z > 0) << 2)  | ((unsigned)(v0.w > 0) << 3)
               | ((unsigned)(v1.x > 0) << 4)  | ((unsigned)(v1.y > 0) << 5)
               | ((unsigned)(v1.z > 0) << 6)  | ((unsigned)(v1.w > 0) << 7)
               | ((unsigned)(v2.x > 0) << 8)  | ((unsigned)(v2.y > 0) << 9)
               | ((unsigned)(v2.z > 0) << 10) | ((unsigned)(v2.w > 0) << 11)
               | ((unsigned)(v3.x > 0) << 12) | ((unsigned)(v3.y > 0) << 13)
               | ((unsigned)(v3.z > 0) << 14) | ((unsigned)(v3.w > 0) << 15);
            maskL[s] = (u16)m;
        }
    }
    __syncthreads();
    if (t < 64) {
        float v = sred[t * 8];
#pragma unroll
        for (int k = 1; k < 8; ++k) v = fmaxf(v, sred[t * 8 + k]);
#pragma unroll
        for (int off = 32; off; off >>= 1) v = fmaxf(v, __shfl_xor(v, off, 64));
        if (t == 0) ssc[64] = v;
    }
    __syncthreads();
    const float mm = wh1rr + ssc[64];
    const float mv = (mm >= 0.f) ? mm : 0.2f * mm;   // lrelu upper bound >= all logits

    // A-fragment write slot (16x16x32 A layout: lane = m + 16*(k>>3), 8 k/lane)
    const int wbase0 = ((sg >> 1) * 4 + (rr >> 4)) * 512
                     + ((rr & 15) + 16 * (2 * (sg & 1))) * 8;

    float4x acc[4][4];
#pragma unroll
    for (int rt = 0; rt < 4; ++rt)
#pragma unroll
        for (int ct = 0; ct < 4; ++ct) acc[rt][ct] = (float4x)0.0f;

    const int bn = lane & 15, bq = lane >> 4, bq8 = bq * 8;
    const long hbase = (long)b * IN_F * NN;
    // wave -> matrix + 64-col slice: waves 0-3 = H cols, 4-7 = G cols
    const u16* Bp = ((wave < 4) ? HbfT : GbfT) + hbase
                  + (long)((wave & 3) * 64 + bn) * NN;

    float lloc = 0.f;

    short8x Aa[4], Ab[4];
    short8x G0[4], G1[4], G2[4], G3[4];
    unsigned mkA, mkB;

    // ---- prologue: mask words chunks 0/1; all 4 B groups of chunk 0 ----
    mkA = maskL[mrow + sg];
    mkB = maskL[mrow + 8 + sg];
    BISSUE(G0, 0, 0)
    BISSUE(G1, 0, 1)
    BISSUE(G2, 0, 2)
    BISSUE(G3, 0, 3)

    for (int kp = 0; kp < 8; ++kp) {
        CHUNK11(kp * 2,     mkA, mkB)
        CHUNK11(kp * 2 + 1, mkB, mkA)
    }

    // ---- reduce l per row (8 partials/row), invert ----
    sred[t] = lloc;
    __syncthreads();
    if (t < 64) {
        float v = sred[t * 8];
#pragma unroll
        for (int k = 1; k < 8; ++k) v += sred[t * 8 + k];
        ssc[t] = 1.0f / v;       // v > 0 always (~half the j's unmasked)
    }
    __syncthreads();

    // ---- scale by 1/l and store (C-layout: col=lane&15, row=(lane>>4)*4+reg)
    u16* dst = (wave < 4) ? PH : PG;
    const int colb = (wave & 3) * 64;
#pragma unroll
    for (int rt = 0; rt < 4; ++rt)
#pragma unroll
        for (int ct = 0; ct < 4; ++ct) {
            const int c = colb + ct * 16 + bn;
#pragma unroll
            for (int reg = 0; reg < 4; ++reg) {
                const int rl = rt * 16 + bq * 4 + reg;
                const float il = ssc[rl];
                const long row = gi0 + rl;
                dst[row * IN_F + c] = f2b(acc[rt][ct][reg] * il);
            }
        }
}

// ---------------------------------------------------------------------------
// epi2: both epilogue GEMMs in one launch, Bw depth-1 ping-pong prefetch.
// ---------------------------------------------------------------------------
#define EPIK(KS, BC, BN_)                                                     \
    {                                                                         \
        if ((KS) < 7) {                                                       \
            _Pragma("unroll") for (int ct = 0; ct < 4; ++ct)                  \
                BN_[ct] = *(const short8x*)(WTrow + ct * 16 * IN_F + ((KS) + 1) * 32 + bq8); \
        }                                                                     \
        short8x A0 = *(const short8x*)&Afrag[(((KS) * 2 + 0) * 64 + lane) * 8]; \
        short8x A1 = *(const short8x*)&Afrag[(((KS) * 2 + 1) * 64 + lane) * 8]; \
        _Pragma("unroll") for (int ct = 0; ct < 4; ++ct) {                    \
            acc[0][ct] = __builtin_amdgcn_mfma_f32_16x16x32_bf16(A0, BC[ct], acc[0][ct], 0, 0, 0); \
            acc[1][ct] = __builtin_amdgcn_mfma_f32_16x16x32_bf16(A1, BC[ct], acc[1][ct], 0, 0, 0); \
        }                                                                     \
    }

__global__ __launch_bounds__(256) void epi2(const u16* __restrict__ PH,
                                            const u16* __restrict__ PG,
                                            const u16* __restrict__ W1T,
                                            const u16* __restrict__ W2T,
                                            float* __restrict__ out)
{
    int bid = blockIdx.x;
    const u16* X;
    const u16* WT;
    float* o;
    if (bid < 512) { X = PH; WT = W1T; o = out; }
    else           { X = PG; WT = W2T; o = out + (long)BB * NN * IN_F; bid -= 512; }

    const int t = threadIdx.x;
    const int wave = t >> 6, lane = t & 63;
    const long i0 = (long)bid * 32;

    __shared__ __align__(16) u16 Afrag[8 * 2 * 64 * 8];   // 16 KB

    const int m = t >> 3, ks0 = t & 7, rt0 = m >> 4, lm = m & 15;
    const u16* xp = X + (i0 + m) * IN_F + ks0 * 32;
#pragma unroll
    for (int q = 0; q < 4; ++q) {
        short8x v = *(const short8x*)(xp + q * 8);
        *(short8x*)&Afrag[((ks0 * 2 + rt0) * 64 + lm + q * 16) * 8] = v;
    }

    const int bn = lane & 15, bq = lane >> 4, bq8 = bq * 8;
    const u16* WTrow = WT + (long)(wave * 64 + bn) * IN_F;

    float4x acc[2][4];
#pragma unroll
    for (int rt = 0; rt < 2; ++rt)
#pragma unroll
        for (int ct = 0; ct < 4; ++ct) acc[rt][ct] = (float4x)0.0f;

    short8x BwA[4], BwB[4];
#pragma unroll
    for (int ct = 0; ct < 4; ++ct)
        BwA[ct] = *(const short8x*)(WTrow + ct * 16 * IN_F + bq8);

    __syncthreads();

#pragma unroll
    for (int kp2 = 0; kp2 < 4; ++kp2) {
        EPIK(kp2 * 2,     BwA, BwB)
        EPIK(kp2 * 2 + 1, BwB, BwA)
    }

#pragma unroll
    for (int rt = 0; rt < 2; ++rt)
#pragma unroll
        for (int ct = 0; ct < 4; ++ct) {
            const int n = wave * 64 + ct * 16 + bn;
#pragma unroll
            for (int reg = 0; reg < 4; ++reg) {
                const long row = i0 + rt * 16 + bq * 4 + reg;
                float v = acc[rt][ct][reg];
                v = (v > 0.f) ? v : (__expf(v) - 1.f);   // ELU
                o[row * IN_F + n] = v;
            }
        }
}

// ---------------------------------------------------------------------------
extern "C" void kernel_launch(void* const* d_in, const int* in_sizes, int n_in,
                              void* d_out, int out_size, void* d_ws, size_t ws_size,
                              hipStream_t stream)
{
    int ih = -1, ig = -1, iadj = -1, iw1 = -1, iw2 = -1, ia = -1;
    for (int i = 0; i < n_in; ++i) {
        int s = in_sizes[i];
        if      (s == BB * NN * NN)   { if (iadj < 0) iadj = i; }
        else if (s == BB * NN * IN_F) { if (ih < 0) ih = i; else if (ig < 0) ig = i; }
        else if (s == IN_F * IN_F)    { if (iw1 < 0) iw1 = i; else if (iw2 < 0) iw2 = i; }
        else if (s == 2 * IN_F)       { if (ia < 0) ia = i; }
    }
    if (ih < 0 || ig < 0 || iadj < 0 || iw1 < 0 || iw2 < 0 || ia < 0) {
        ih = 0; iadj = 1; ig = 2; iw1 = 3; iw2 = 4; ia = 5;
    }
    const float* h     = (const float*)d_in[ih];
    const int*   adj   = (const int*)  d_in[iadj];
    const float* lrgt1 = (const float*)d_in[ig];
    const float* W1    = (const float*)d_in[iw1];
    const float* W2    = (const float*)d_in[iw2];
    const float* a     = (const float*)d_in[ia];
    float* out = (float*)d_out;

    // ws layout — 33,949,696 B total (<= proven-available 34,212,096 B)
    float* ws   = (float*)d_ws;
    float* v1   = ws;                       // 256
    float* v2   = v1 + IN_F;                // 256
    float* Wh1  = v2 + IN_F;                // 16384
    float* Wh2  = Wh1 + BB * NN;            // 16384
    u16* W1T  = (u16*)(Wh2 + BB * NN);      // 65536 bf16
    u16* W2T  = W1T + IN_F * IN_F;          // 65536
    u16* HbfT = W2T + IN_F * IN_F;          // 8*256*2048
    u16* GbfT = HbfT + (long)BB * IN_F * NN;
    u16* PH   = GbfT + (long)BB * IN_F * NN;
    u16* PG   = PH + (long)BB * NN * IN_F;

    const int nrows = BB * NN;

    prep     <<<8321,        256, 0, stream>>>(h, lrgt1, W1, W2, a,
                                               HbfT, GbfT, W1T, W2T, v1, v2);
    rowdots  <<<nrows / 4,   256, 0, stream>>>(h, v1, v2, Wh1, Wh2);
    attn_mfma<<<nrows / 64,  512, 0, stream>>>(adj, HbfT, GbfT, Wh1, Wh2, PH, PG);
    epi2     <<<2 * nrows / 32, 256, 0, stream>>>(PH, PG, W1T, W2T, out);
}